// Round 1
// baseline (1509.258 us; speedup 1.0000x reference)
//
#include <hip/hip_runtime.h>

#define BB 8
#define CC 256
#define NN 4096
#define MALL 320          // 32 f rows + 32 g rows + 256 h rows
#define LOG2E 1.44269504088896340736f

// ---------------------------------------------------------------------------
// ws layout (floats):
//   fgh : [B][320][N]   rows 0-31=f, 32-63=g, 64-319=h      (10,485,760)
//   pm  : [B][4][N]     partial row-max (base-2 scale)      (   131,072)
//   ps  : [B][4][N]     partial row-sum                     (   131,072)
//   m2  : [B][N]        merged row-max                      (    32,768)
//   invD: [B][N]        1 / softmax denom                   (    32,768)
// total ≈ 41.25 MB
// ---------------------------------------------------------------------------

// Kernel 1: fgh[b][o][i] = W_all[o][:] . x[b][:][i] + bias[o]
// GEMM M=320, K=256, Ncols=4096 per batch. 64x64 tiles, 4x4 register block.
__global__ __launch_bounds__(256) void k_fgh(
    const float* __restrict__ x,
    const float* __restrict__ Wf, const float* __restrict__ bf,
    const float* __restrict__ Wg, const float* __restrict__ bg,
    const float* __restrict__ Wh, const float* __restrict__ bh,
    float* __restrict__ fgh)
{
  __shared__ float Wl[64][68];   // [o][c]
  __shared__ float Xl[64][68];   // [c][i]
  const int b = blockIdx.z, ot0 = blockIdx.y * 64, i0 = blockIdx.x * 64;
  const int t = threadIdx.x, tx = t & 15, ty = t >> 4;
  float acc[4][4] = {};
  for (int k0 = 0; k0 < CC; k0 += 64) {
    __syncthreads();
    // stage W tile [64 o][64 c]
    for (int l = t; l < 1024; l += 256) {
      int row = l >> 4, cq = (l & 15) * 4;
      int o = ot0 + row;
      const float* wsrc = (o < 32) ? (Wf + (size_t)o * CC)
                        : (o < 64) ? (Wg + (size_t)(o - 32) * CC)
                                   : (Wh + (size_t)(o - 64) * CC);
      *(float4*)&Wl[row][cq] = *(const float4*)(wsrc + k0 + cq);
    }
    // stage X tile [64 c][64 i]
    for (int l = t; l < 1024; l += 256) {
      int row = l >> 4, iq = (l & 15) * 4;
      *(float4*)&Xl[row][iq] =
          *(const float4*)(x + ((size_t)b * CC + k0 + row) * NN + i0 + iq);
    }
    __syncthreads();
    #pragma unroll 8
    for (int kk = 0; kk < 64; ++kk) {
      float a[4];
      #pragma unroll
      for (int r = 0; r < 4; ++r) a[r] = Wl[ty * 4 + r][kk];
      float4 bv = *(float4*)&Xl[kk][tx * 4];
      float bb[4] = {bv.x, bv.y, bv.z, bv.w};
      #pragma unroll
      for (int r = 0; r < 4; ++r)
        #pragma unroll
        for (int s = 0; s < 4; ++s) acc[r][s] += a[r] * bb[s];
    }
  }
  #pragma unroll
  for (int r = 0; r < 4; ++r) {
    int o = ot0 + ty * 4 + r;
    float bias = (o < 32) ? bf[o] : (o < 64) ? bg[o - 32] : bh[o - 64];
    float4 v;
    v.x = acc[r][0] + bias; v.y = acc[r][1] + bias;
    v.z = acc[r][2] + bias; v.w = acc[r][3] + bias;
    *(float4*)(fgh + ((size_t)b * MALL + o) * NN + i0 + tx * 4) = v;
  }
}

// Kernel 2a: per-row partial softmax stats over a 1024-wide j slice.
// Row k per thread; online (max,sum) in base-2.
__global__ __launch_bounds__(256) void k_stats(
    const float* __restrict__ fgh, float* __restrict__ pm, float* __restrict__ ps)
{
  __shared__ float Fl[32][256];
  __shared__ float Gl[32][128];
  const int b = blockIdx.z, js = blockIdx.y, k0 = blockIdx.x * 256;
  const float* f = fgh + (size_t)b * MALL * NN;
  const float* g = f + (size_t)32 * NN;
  const int t = threadIdx.x;
  for (int l = t; l < 2048; l += 256) {
    int o = l >> 6, kq = (l & 63) * 4;
    *(float4*)&Fl[o][kq] = *(const float4*)(f + (size_t)o * NN + k0 + kq);
  }
  __syncthreads();
  float fr[32];
  #pragma unroll
  for (int o = 0; o < 32; ++o) fr[o] = Fl[o][t];
  float m = -1e30f, s = 0.0f;
  for (int j0 = js * 1024; j0 < js * 1024 + 1024; j0 += 128) {
    __syncthreads();
    for (int l = t; l < 1024; l += 256) {
      int o = l >> 5, jq = (l & 31) * 4;
      *(float4*)&Gl[o][jq] = *(const float4*)(g + (size_t)o * NN + j0 + jq);
    }
    __syncthreads();
    for (int j = 0; j < 128; j += 4) {
      float l2[4];
      #pragma unroll
      for (int u = 0; u < 4; ++u) {
        float a0 = 0, a1 = 0, a2 = 0, a3 = 0;
        #pragma unroll
        for (int o = 0; o < 32; o += 4) {
          a0 += fr[o + 0] * Gl[o + 0][j + u];
          a1 += fr[o + 1] * Gl[o + 1][j + u];
          a2 += fr[o + 2] * Gl[o + 2][j + u];
          a3 += fr[o + 3] * Gl[o + 3][j + u];
        }
        l2[u] = ((a0 + a1) + (a2 + a3)) * LOG2E;
      }
      float mx = fmaxf(fmaxf(l2[0], l2[1]), fmaxf(l2[2], l2[3]));
      float mn = fmaxf(m, mx);
      s = s * exp2f(m - mn)
        + ((exp2f(l2[0] - mn) + exp2f(l2[1] - mn))
         + (exp2f(l2[2] - mn) + exp2f(l2[3] - mn)));
      m = mn;
    }
  }
  size_t idx = ((size_t)b * 4 + js) * NN + k0 + t;
  pm[idx] = m;
  ps[idx] = s;
}

// Kernel 2b: merge 4 j-slice partials -> m2, invD
__global__ __launch_bounds__(256) void k_merge(
    const float* __restrict__ pm, const float* __restrict__ ps,
    float* __restrict__ m2, float* __restrict__ invD)
{
  int idx = blockIdx.x * 256 + threadIdx.x;       // b*N + k
  int b = idx >> 12, k = idx & 4095;
  float m = -1e30f;
  #pragma unroll
  for (int js = 0; js < 4; ++js)
    m = fmaxf(m, pm[((size_t)b * 4 + js) * NN + k]);
  float D = 0.0f;
  #pragma unroll
  for (int js = 0; js < 4; ++js) {
    size_t q = ((size_t)b * 4 + js) * NN + k;
    D += ps[q] * exp2f(pm[q] - m);
  }
  m2[idx] = m;
  invD[idx] = 1.0f / D;
}

// Kernel 3: out[b][c][i] = gamma * sum_k h[c,k] * p[k,i] + x[b][c][i]
//   p[k,i] = exp2(l2[k,i] - m2[k]) * invD[k],  l2 = (f_k . g_i)*log2e
// Block: 128 c x 64 i, K-chunks of 64. 8x4 register block per thread.
__global__ __launch_bounds__(256, 2) void k_out(
    const float* __restrict__ fgh, const float* __restrict__ m2v,
    const float* __restrict__ invDv, const float* __restrict__ x,
    const float* __restrict__ gamma, float* __restrict__ out)
{
  __shared__ float Gl[32][68];
  __shared__ float Fl[32][68];
  __shared__ float Pl[64][68];
  __shared__ float HT[64][132];   // [kk][c_local], transposed h tile
  const int b = blockIdx.z, c0 = blockIdx.y * 128, i0 = blockIdx.x * 64;
  const float* f = fgh + (size_t)b * MALL * NN;
  const float* g = f + (size_t)32 * NN;
  const float* h = f + (size_t)64 * NN;
  const float* m2 = m2v + (size_t)b * NN;
  const float* invD = invDv + (size_t)b * NN;
  const int t = threadIdx.x, tx = t & 15, ty = t >> 4;
  // stage G tile once: g[o][i0..i0+63]
  for (int l = t; l < 512; l += 256) {
    int o = l >> 4, iq = (l & 15) * 4;
    *(float4*)&Gl[o][iq] = *(const float4*)(g + (size_t)o * NN + i0 + iq);
  }
  float acc[8][4] = {};
  for (int k0 = 0; k0 < NN; k0 += 64) {
    __syncthreads();
    // stage F chunk [32 o][64 k]
    for (int l = t; l < 512; l += 256) {
      int o = l >> 4, kq = (l & 15) * 4;
      *(float4*)&Fl[o][kq] = *(const float4*)(f + (size_t)o * NN + k0 + kq);
    }
    // stage H chunk transposed: HT[kk][cl] = h[c0+cl][k0+kk]
    {
      int kk = t & 63, cl0 = t >> 6;
      for (int cl = cl0; cl < 128; cl += 4)
        HT[kk][cl] = h[(size_t)(c0 + cl) * NN + k0 + kk];
    }
    __syncthreads();
    // logits + p for this chunk: thread owns k = ty*4+r, i = tx*4+s
    float pl[4][4] = {};
    #pragma unroll 8
    for (int o = 0; o < 32; ++o) {
      float4 fv = *(float4*)&Fl[o][ty * 4];
      float4 gv = *(float4*)&Gl[o][tx * 4];
      float fa[4] = {fv.x, fv.y, fv.z, fv.w};
      float ga[4] = {gv.x, gv.y, gv.z, gv.w};
      #pragma unroll
      for (int r = 0; r < 4; ++r)
        #pragma unroll
        for (int s = 0; s < 4; ++s) pl[r][s] += fa[r] * ga[s];
    }
    #pragma unroll
    for (int r = 0; r < 4; ++r) {
      int k = k0 + ty * 4 + r;
      float mm = m2[k], dd = invD[k];
      float4 v;
      v.x = exp2f(pl[r][0] * LOG2E - mm) * dd;
      v.y = exp2f(pl[r][1] * LOG2E - mm) * dd;
      v.z = exp2f(pl[r][2] * LOG2E - mm) * dd;
      v.w = exp2f(pl[r][3] * LOG2E - mm) * dd;
      *(float4*)&Pl[ty * 4 + r][tx * 4] = v;
    }
    __syncthreads();
    // accumulate: acc[r][s] += HT[kk][ty*8+r] * Pl[kk][tx*4+s]
    #pragma unroll 4
    for (int kk = 0; kk < 64; ++kk) {
      float4 pv = *(float4*)&Pl[kk][tx * 4];
      float4 h0 = *(float4*)&HT[kk][ty * 8];
      float4 h1 = *(float4*)&HT[kk][ty * 8 + 4];
      float hr[8] = {h0.x, h0.y, h0.z, h0.w, h1.x, h1.y, h1.z, h1.w};
      float pr[4] = {pv.x, pv.y, pv.z, pv.w};
      #pragma unroll
      for (int r = 0; r < 8; ++r)
        #pragma unroll
        for (int s = 0; s < 4; ++s) acc[r][s] += hr[r] * pr[s];
    }
  }
  float gm = gamma[0];
  #pragma unroll
  for (int r = 0; r < 8; ++r) {
    int c = c0 + ty * 8 + r;
    size_t off = ((size_t)b * CC + c) * NN + i0 + tx * 4;
    float4 xv = *(const float4*)(x + off);
    float4 ov;
    ov.x = gm * acc[r][0] + xv.x;
    ov.y = gm * acc[r][1] + xv.y;
    ov.z = gm * acc[r][2] + xv.z;
    ov.w = gm * acc[r][3] + xv.w;
    *(float4*)(out + off) = ov;
  }
}

extern "C" void kernel_launch(void* const* d_in, const int* in_sizes, int n_in,
                              void* d_out, int out_size, void* d_ws, size_t ws_size,
                              hipStream_t stream)
{
  const float* x     = (const float*)d_in[0];
  const float* Wf    = (const float*)d_in[1];
  const float* bf    = (const float*)d_in[2];
  const float* Wg    = (const float*)d_in[3];
  const float* bg    = (const float*)d_in[4];
  const float* Wh    = (const float*)d_in[5];
  const float* bh    = (const float*)d_in[6];
  const float* gamma = (const float*)d_in[7];
  float* out = (float*)d_out;

  float* w    = (float*)d_ws;
  float* fgh  = w;                       // 10,485,760
  float* pm   = w + 10485760;            //    131,072
  float* ps   = pm + 131072;             //    131,072
  float* m2   = ps + 131072;             //     32,768
  float* invD = m2 + 32768;              //     32,768

  k_fgh  <<<dim3(64, 5, 8),  256, 0, stream>>>(x, Wf, bf, Wg, bg, Wh, bh, fgh);
  k_stats<<<dim3(16, 4, 8),  256, 0, stream>>>(fgh, pm, ps);
  k_merge<<<dim3(128),       256, 0, stream>>>(pm, ps, m2, invD);
  k_out  <<<dim3(64, 2, 8),  256, 0, stream>>>(fgh, m2, invD, x, gamma, out);
}

// Round 2
// 289.157 us; speedup vs baseline: 5.2195x; 5.2195x over previous
//
#include <hip/hip_runtime.h>
#include <hip/hip_bf16.h>

#define BB 8
#define CC 256
#define NN 4096
#define MALL 320          // 32 f rows + 32 g rows + 256 h rows
#define LOG2E 1.44269504088896340736f

typedef __attribute__((ext_vector_type(8))) short short8;
typedef __attribute__((ext_vector_type(4))) float f32x4;

static __device__ __forceinline__ unsigned short f2b(float x) {
  __hip_bfloat16 h = __float2bfloat16(x);   // RNE
  return *reinterpret_cast<unsigned short*>(&h);
}

// ---------------------------------------------------------------------------
// ws layout:
//   fgh  : [B][320][N] f32   rows 0-31=f, 32-63=g, 64-319=h   (10,485,760 f)
//   m2   : [B][N] f32        row max (base-2 units)           (32,768 f)
//   invD : [B][N] f32        1/denom                          (32,768 f)
//   fA   : [B][256 kg][64 l][8 e] bf16  A-frags of f^T*log2e  (1,048,576 h)
//   gB   : [B][256 ig][64 l][8 e] bf16  B-frags of g          (1,048,576 h)
//   hA   : [B][16 cg][128 kc][64 l][8 e] bf16 A-frags of h    (8,388,608 h)
// total ≈ 60.3 MB
// Frag conventions (mfma_f32_16x16x32_bf16, m89/m91-verified):
//   A[m][k]: lane l holds m=l&15, k=(l>>4)*8+e
//   B[k][n]: lane l holds n=l&15, k=(l>>4)*8+e
//   D[m][n]: lane l reg r holds m=(l>>4)*4+r, n=l&15
// ---------------------------------------------------------------------------

// Kernel 1: fgh[b][o][i] = W_all[o][:] . x[b][:][i] + bias[o]   (fp32 GEMM)
__global__ __launch_bounds__(256) void k_fgh(
    const float* __restrict__ x,
    const float* __restrict__ Wf, const float* __restrict__ bf,
    const float* __restrict__ Wg, const float* __restrict__ bg,
    const float* __restrict__ Wh, const float* __restrict__ bh,
    float* __restrict__ fgh)
{
  __shared__ float Wl[64][68];
  __shared__ float Xl[64][68];
  const int b = blockIdx.z, ot0 = blockIdx.y * 64, i0 = blockIdx.x * 64;
  const int t = threadIdx.x, tx = t & 15, ty = t >> 4;
  float acc[4][4] = {};
  for (int k0 = 0; k0 < CC; k0 += 64) {
    __syncthreads();
    for (int l = t; l < 1024; l += 256) {
      int row = l >> 4, cq = (l & 15) * 4;
      int o = ot0 + row;
      const float* wsrc = (o < 32) ? (Wf + (size_t)o * CC)
                        : (o < 64) ? (Wg + (size_t)(o - 32) * CC)
                                   : (Wh + (size_t)(o - 64) * CC);
      *(float4*)&Wl[row][cq] = *(const float4*)(wsrc + k0 + cq);
    }
    for (int l = t; l < 1024; l += 256) {
      int row = l >> 4, iq = (l & 15) * 4;
      *(float4*)&Xl[row][iq] =
          *(const float4*)(x + ((size_t)b * CC + k0 + row) * NN + i0 + iq);
    }
    __syncthreads();
    #pragma unroll 8
    for (int kk = 0; kk < 64; ++kk) {
      float a[4];
      #pragma unroll
      for (int r = 0; r < 4; ++r) a[r] = Wl[ty * 4 + r][kk];
      float4 bv = *(float4*)&Xl[kk][tx * 4];
      float bb[4] = {bv.x, bv.y, bv.z, bv.w};
      #pragma unroll
      for (int r = 0; r < 4; ++r)
        #pragma unroll
        for (int s = 0; s < 4; ++s) acc[r][s] += a[r] * bb[s];
    }
  }
  #pragma unroll
  for (int r = 0; r < 4; ++r) {
    int o = ot0 + ty * 4 + r;
    float bias = (o < 32) ? bf[o] : (o < 64) ? bg[o - 32] : bh[o - 64];
    float4 v;
    v.x = acc[r][0] + bias; v.y = acc[r][1] + bias;
    v.z = acc[r][2] + bias; v.w = acc[r][3] + bias;
    *(float4*)(fgh + ((size_t)b * MALL + o) * NN + i0 + tx * 4) = v;
  }
}

// Kernel 2: f,g fp32 -> frag-ready bf16 (fA scaled by LOG2E), via LDS bounce.
__global__ __launch_bounds__(256) void k_prep_fg(
    const float* __restrict__ fgh,
    unsigned short* __restrict__ fA, unsigned short* __restrict__ gB)
{
  __shared__ float fl[32][68];
  __shared__ float gl[32][68];
  const int b = blockIdx.y, k0 = blockIdx.x * 64;
  const float* f = fgh + (size_t)b * MALL * NN;
  const float* g = f + (size_t)32 * NN;
  const int t = threadIdx.x;
  for (int l = t; l < 512; l += 256) {
    int o = l >> 4, kq = (l & 15) * 4;
    *(float4*)&fl[o][kq] = *(const float4*)(f + (size_t)o * NN + k0 + kq);
    *(float4*)&gl[o][kq] = *(const float4*)(g + (size_t)o * NN + k0 + kq);
  }
  __syncthreads();
  const int kgl = t >> 6, l = t & 63;
  const int m = l & 15, ob = (l >> 4) * 8;
  short8 vf, vg;
  #pragma unroll
  for (int e = 0; e < 8; ++e) {
    vf[e] = (short)f2b(fl[ob + e][kgl * 16 + m] * LOG2E);
    vg[e] = (short)f2b(gl[ob + e][kgl * 16 + m]);
  }
  size_t kg = (size_t)blockIdx.x * 4 + kgl;
  *(short8*)(fA + (((size_t)b * 256 + kg) * 64 + l) * 8) = vf;
  *(short8*)(gB + (((size_t)b * 256 + kg) * 64 + l) * 8) = vg;
}

// Kernel 3: h fp32 -> frag-ready bf16 hA
__global__ __launch_bounds__(256) void k_prep_h(
    const float* __restrict__ fgh, unsigned short* __restrict__ hA)
{
  const int b = blockIdx.y, cg = blockIdx.x;
  const float* h = fgh + (size_t)b * MALL * NN + (size_t)64 * NN;
  const int t = threadIdx.x, l = t & 63, kc0 = t >> 6;
  const int row = cg * 16 + (l & 15), colb = (l >> 4) * 8;
  for (int kc = kc0; kc < 128; kc += 4) {
    const float* src = h + (size_t)row * NN + kc * 32 + colb;
    float4 a = *(const float4*)src;
    float4 c = *(const float4*)(src + 4);
    short8 v;
    v[0] = (short)f2b(a.x); v[1] = (short)f2b(a.y);
    v[2] = (short)f2b(a.z); v[3] = (short)f2b(a.w);
    v[4] = (short)f2b(c.x); v[5] = (short)f2b(c.y);
    v[6] = (short)f2b(c.z); v[7] = (short)f2b(c.w);
    *(short8*)(hA + ((((size_t)b * 16 + cg) * 128 + kc) * 64 + l) * 8) = v;
  }
}

// Kernel 4: row softmax stats via MFMA. Wave owns 16 k-rows; 2 passes over j.
__global__ __launch_bounds__(256) void k_stats(
    const unsigned short* __restrict__ fA, const unsigned short* __restrict__ gB,
    float* __restrict__ m2, float* __restrict__ invD)
{
  const int b = blockIdx.y, ktile = blockIdx.x;
  const int t = threadIdx.x, w = t >> 6, l = t & 63;
  const size_t kg = (size_t)ktile * 4 + w;
  short8 afrag = *(const short8*)(fA + (((size_t)b * 256 + kg) * 64 + l) * 8);
  const unsigned short* gb = gB + (size_t)b * 256 * 64 * 8;
  f32x4 zero = {0.f, 0.f, 0.f, 0.f};
  float mrow[4] = {-1e30f, -1e30f, -1e30f, -1e30f};
  #pragma unroll 4
  for (int jg = 0; jg < 256; ++jg) {
    short8 bfrag = *(const short8*)(gb + ((size_t)jg * 64 + l) * 8);
    f32x4 d = __builtin_amdgcn_mfma_f32_16x16x32_bf16(afrag, bfrag, zero, 0, 0, 0);
    #pragma unroll
    for (int r = 0; r < 4; ++r) mrow[r] = fmaxf(mrow[r], d[r]);
  }
  #pragma unroll
  for (int mk = 1; mk < 16; mk <<= 1)
    #pragma unroll
    for (int r = 0; r < 4; ++r) mrow[r] = fmaxf(mrow[r], __shfl_xor(mrow[r], mk));
  float srow[4] = {0.f, 0.f, 0.f, 0.f};
  #pragma unroll 4
  for (int jg = 0; jg < 256; ++jg) {
    short8 bfrag = *(const short8*)(gb + ((size_t)jg * 64 + l) * 8);
    f32x4 d = __builtin_amdgcn_mfma_f32_16x16x32_bf16(afrag, bfrag, zero, 0, 0, 0);
    #pragma unroll
    for (int r = 0; r < 4; ++r) srow[r] += exp2f(d[r] - mrow[r]);
  }
  #pragma unroll
  for (int mk = 1; mk < 16; mk <<= 1)
    #pragma unroll
    for (int r = 0; r < 4; ++r) srow[r] += __shfl_xor(srow[r], mk);
  if ((l & 15) == 0) {
    #pragma unroll
    for (int r = 0; r < 4; ++r) {
      size_t idx = (size_t)b * NN + ktile * 64 + w * 16 + (l >> 4) * 4 + r;
      m2[idx] = mrow[r];
      invD[idx] = 1.0f / srow[r];
    }
  }
}

// Kernel 5: out[b][c][i] = gamma * sum_k h[c,k] p[k,i] + x[b][c][i]  (MFMA)
// 8 waves: wave w computes S-frag (kg=w&1, ig=w>>1) and PV rows w*32..w*32+32.
__global__ __launch_bounds__(512, 4) void k_out(
    const unsigned short* __restrict__ fA, const unsigned short* __restrict__ gB,
    const unsigned short* __restrict__ hA,
    const float* __restrict__ m2v, const float* __restrict__ invDv,
    const float* __restrict__ x, const float* __restrict__ gamma,
    float* __restrict__ out)
{
  __shared__ unsigned short pF[4 * 64 * 8];   // [ig][lane][e] frag-ready P
  const int b = blockIdx.y, i0 = blockIdx.x * 64;
  const int t = threadIdx.x, w = t >> 6, l = t & 63;
  const int kg_s = w & 1, ig_s = w >> 1;
  short8 gfrag = *(const short8*)(gB +
      (((size_t)b * 256 + (i0 >> 4) + ig_s) * 64 + l) * 8);
  const float* m2 = m2v + (size_t)b * NN;
  const float* invD = invDv + (size_t)b * NN;
  f32x4 zero = {0.f, 0.f, 0.f, 0.f};
  f32x4 acc[2][4] = {};
  // precomputed LDS slot for this thread's P b64 write
  const int kk0 = kg_s * 16 + (l >> 4) * 4;           // 0,4,8,..,28
  const int lp = ((kk0 >> 3) << 4) | (l & 15);
  unsigned short* pdst = &pF[(ig_s * 64 + lp) * 8 + (kk0 & 7)];
  for (int ch = 0; ch < 128; ++ch) {
    // S-frag: rows k0+kg_s*16 .. +16, cols i0+ig_s*16 .. +16
    short8 afrag = *(const short8*)(fA +
        (((size_t)b * 256 + ch * 2 + kg_s) * 64 + l) * 8);
    f32x4 s = __builtin_amdgcn_mfma_f32_16x16x32_bf16(afrag, gfrag, zero, 0, 0, 0);
    const int kb = ch * 32 + kk0;
    float4 mm = *(const float4*)(m2 + kb);
    float4 dd = *(const float4*)(invD + kb);
    ushort4 pv;
    pv.x = f2b(exp2f(s[0] - mm.x) * dd.x);
    pv.y = f2b(exp2f(s[1] - mm.y) * dd.y);
    pv.z = f2b(exp2f(s[2] - mm.z) * dd.z);
    pv.w = f2b(exp2f(s[3] - mm.w) * dd.w);
    // h A-frags for this chunk (issue before barrier to hide latency)
    short8 h0 = *(const short8*)(hA +
        ((((size_t)b * 16 + w * 2 + 0) * 128 + ch) * 64 + l) * 8);
    short8 h1 = *(const short8*)(hA +
        ((((size_t)b * 16 + w * 2 + 1) * 128 + ch) * 64 + l) * 8);
    *(ushort4*)pdst = pv;
    __syncthreads();
    short8 pf0 = *(const short8*)&pF[(0 * 64 + l) * 8];
    short8 pf1 = *(const short8*)&pF[(1 * 64 + l) * 8];
    short8 pf2 = *(const short8*)&pF[(2 * 64 + l) * 8];
    short8 pf3 = *(const short8*)&pF[(3 * 64 + l) * 8];
    acc[0][0] = __builtin_amdgcn_mfma_f32_16x16x32_bf16(h0, pf0, acc[0][0], 0, 0, 0);
    acc[0][1] = __builtin_amdgcn_mfma_f32_16x16x32_bf16(h0, pf1, acc[0][1], 0, 0, 0);
    acc[0][2] = __builtin_amdgcn_mfma_f32_16x16x32_bf16(h0, pf2, acc[0][2], 0, 0, 0);
    acc[0][3] = __builtin_amdgcn_mfma_f32_16x16x32_bf16(h0, pf3, acc[0][3], 0, 0, 0);
    acc[1][0] = __builtin_amdgcn_mfma_f32_16x16x32_bf16(h1, pf0, acc[1][0], 0, 0, 0);
    acc[1][1] = __builtin_amdgcn_mfma_f32_16x16x32_bf16(h1, pf1, acc[1][1], 0, 0, 0);
    acc[1][2] = __builtin_amdgcn_mfma_f32_16x16x32_bf16(h1, pf2, acc[1][2], 0, 0, 0);
    acc[1][3] = __builtin_amdgcn_mfma_f32_16x16x32_bf16(h1, pf3, acc[1][3], 0, 0, 0);
    __syncthreads();
  }
  const float gm = gamma[0];
  #pragma unroll
  for (int cg2 = 0; cg2 < 2; ++cg2)
    #pragma unroll
    for (int ig = 0; ig < 4; ++ig)
      #pragma unroll
      for (int r = 0; r < 4; ++r) {
        int c = w * 32 + cg2 * 16 + (l >> 4) * 4 + r;
        int i = i0 + ig * 16 + (l & 15);
        size_t off = ((size_t)b * CC + c) * NN + i;
        out[off] = gm * acc[cg2][ig][r] + x[off];
      }
}

extern "C" void kernel_launch(void* const* d_in, const int* in_sizes, int n_in,
                              void* d_out, int out_size, void* d_ws, size_t ws_size,
                              hipStream_t stream)
{
  const float* x     = (const float*)d_in[0];
  const float* Wf    = (const float*)d_in[1];
  const float* bf    = (const float*)d_in[2];
  const float* Wg    = (const float*)d_in[3];
  const float* bg    = (const float*)d_in[4];
  const float* Wh    = (const float*)d_in[5];
  const float* bh    = (const float*)d_in[6];
  const float* gamma = (const float*)d_in[7];
  float* out = (float*)d_out;

  float* ws   = (float*)d_ws;
  float* fgh  = ws;                          // 10,485,760 f32
  float* m2   = fgh + 10485760;              //     32,768 f32
  float* invD = m2 + 32768;                  //     32,768 f32
  unsigned short* fA = (unsigned short*)(invD + 32768);   // 1,048,576 bf16
  unsigned short* gB = fA + 1048576;                      // 1,048,576 bf16
  unsigned short* hA = gB + 1048576;                      // 8,388,608 bf16

  k_fgh    <<<dim3(64, 5, 8), 256, 0, stream>>>(x, Wf, bf, Wg, bg, Wh, bh, fgh);
  k_prep_fg<<<dim3(64, 8),    256, 0, stream>>>(fgh, fA, gB);
  k_prep_h <<<dim3(16, 8),    256, 0, stream>>>(fgh, hA);
  k_stats  <<<dim3(64, 8),    256, 0, stream>>>(fA, gB, m2, invD);
  k_out    <<<dim3(64, 8),    512, 0, stream>>>(fA, gB, hA, m2, invD, x, gamma, out);
}

// Round 3
// 237.888 us; speedup vs baseline: 6.3444x; 1.2155x over previous
//
#include <hip/hip_runtime.h>
#include <hip/hip_bf16.h>

#define BB 8
#define CC 256
#define NN 4096
#define LOG2E 1.44269504088896340736f

typedef __attribute__((ext_vector_type(8))) short short8;
typedef __attribute__((ext_vector_type(4))) float f32x4;

static __device__ __forceinline__ unsigned short f2b(float x) {
  __hip_bfloat16 h = __float2bfloat16(x);   // RNE
  return *reinterpret_cast<unsigned short*>(&h);
}

// ---------------------------------------------------------------------------
// ws layout (bytes):
//   m2   @ 0        : [B][N] f32   row max (base-2 units)        131072
//   invD @ 131072   : [B][N] f32   1/denom                       131072
//   wA   @ 262144   : [20 mg][8 kg][64 l][8 e] bf16 W A-frags    163840
//   ball @ 425984   : [320] f32 biases (f rows pre-scaled LOG2E)   1280
//   fA   @ 427520   : [B][256 kg][64 l][8 e] bf16 (f^T*LOG2E)   2097152
//   gB   @ 2524672  : [B][256 ig][64 l][8 e] bf16               2097152
//   hA   @ 4621824  : [B][16 cg][128 kc][64 l][8 e] bf16       16777216
// total ≈ 21.4 MB
// Frag conventions (mfma_f32_16x16x32_bf16, m89/m91-verified):
//   A[m][k]: lane l holds m=l&15, k=(l>>4)*8+e
//   B[k][n]: lane l holds n=l&15, k=(l>>4)*8+e
//   D[m][n]: lane l reg r holds m=(l>>4)*4+r, n=l&15
// ---------------------------------------------------------------------------

// Kernel 0: W -> A-frags (bf16), LOG2E folded into f rows; biases -> ball.
__global__ __launch_bounds__(256) void k_wprep(
    const float* __restrict__ Wf, const float* __restrict__ bfv,
    const float* __restrict__ Wg, const float* __restrict__ bgv,
    const float* __restrict__ Wh, const float* __restrict__ bhv,
    unsigned short* __restrict__ wA, float* __restrict__ ball)
{
  const int t = threadIdx.x;
  const int fi = blockIdx.x * 4 + (t >> 6);   // frag index 0..159 (mg*8+kg)
  const int l = t & 63;
  const int mg = fi >> 3, kg = fi & 7;
  const int o = mg * 16 + (l & 15);
  const int c0 = kg * 32 + (l >> 4) * 8;
  const float* src; float scale = 1.0f;
  if (o < 32)      { src = Wf + (size_t)o * CC; scale = LOG2E; }
  else if (o < 64) { src = Wg + (size_t)(o - 32) * CC; }
  else             { src = Wh + (size_t)(o - 64) * CC; }
  float4 a = *(const float4*)(src + c0);
  float4 c = *(const float4*)(src + c0 + 4);
  short8 v;
  v[0] = (short)f2b(a.x * scale); v[1] = (short)f2b(a.y * scale);
  v[2] = (short)f2b(a.z * scale); v[3] = (short)f2b(a.w * scale);
  v[4] = (short)f2b(c.x * scale); v[5] = (short)f2b(c.y * scale);
  v[6] = (short)f2b(c.z * scale); v[7] = (short)f2b(c.w * scale);
  *(short8*)(wA + (size_t)fi * 512 + l * 8) = v;
  if (blockIdx.x == 0 && t < 320)
    ball[t] = (t < 32) ? bfv[t] * LOG2E : (t < 64) ? bgv[t - 32] : bhv[t - 64];
}

// Kernel 1: fused projection GEMM (bf16 MFMA) -> frag-ready fA/gB/hA.
// Block: all 320 outputs x 64 positions. 8 waves, 10 acc frags each.
__global__ __launch_bounds__(512) void k_fgh(
    const float* __restrict__ x, const unsigned short* __restrict__ wA,
    const float* __restrict__ ball,
    unsigned short* __restrict__ fA, unsigned short* __restrict__ gB,
    unsigned short* __restrict__ hA)
{
  __shared__ __align__(16) char smem[41984];       // max(xb 8KB, TL 41KB)
  unsigned short* xb = (unsigned short*)smem;      // [8 frag][64 l][8 e]
  unsigned short* TL = (unsigned short*)smem;      // [64 i][328 o] bf16
  const int bid = blockIdx.x;
  const int b = bid & 7, i0 = (bid >> 3) * 64;     // batch pinned to XCD
  const int t = threadIdx.x, w = t >> 6, l = t & 63;
  const int ig_w = w & 3, mg0 = (w >> 2) * 10;
  f32x4 acc[10] = {};
  for (int cc = 0; cc < 4; ++cc) {                 // c-chunks of 64
    __syncthreads();
    {  // stage x[cc*64..+64][i0..i0+64] as 8 B-frags (bf16)
      short8 v;
      const float* xp = x + ((size_t)b * CC + cc * 64 + w * 8) * NN + i0 + l;
      #pragma unroll
      for (int e = 0; e < 8; ++e) v[e] = (short)f2b(xp[(size_t)e * NN]);
      int frag = (w >> 2) * 4 + (l >> 4);
      int lp = (w & 3) * 16 + (l & 15);
      *(short8*)(xb + (frag * 64 + lp) * 8) = v;
    }
    __syncthreads();
    #pragma unroll
    for (int kg2 = 0; kg2 < 2; ++kg2) {
      int kg = cc * 2 + kg2;
      short8 bfrag = *(const short8*)(xb + ((kg2 * 4 + ig_w) * 64 + l) * 8);
      #pragma unroll
      for (int j = 0; j < 10; ++j) {
        short8 afrag = *(const short8*)(wA +
            ((size_t)((mg0 + j) * 8 + kg)) * 512 + l * 8);
        acc[j] = __builtin_amdgcn_mfma_f32_16x16x32_bf16(afrag, bfrag, acc[j], 0, 0, 0);
      }
    }
  }
  __syncthreads();
  // D-frags (+bias) -> transpose tile TL[i][o]
  #pragma unroll
  for (int j = 0; j < 10; ++j) {
    int ob = (mg0 + j) * 16 + (l >> 4) * 4;
    float4 bl = *(const float4*)(ball + ob);
    int irow = ig_w * 16 + (l & 15);
    ushort4 pv;
    pv.x = f2b(acc[j][0] + bl.x); pv.y = f2b(acc[j][1] + bl.y);
    pv.z = f2b(acc[j][2] + bl.z); pv.w = f2b(acc[j][3] + bl.w);
    *(ushort4*)(TL + irow * 328 + ob) = pv;
  }
  __syncthreads();
  // pack fA (o 0..31, *already* LOG2E-scaled) and gB (o 32..63)
  if (t < 256) {
    int kg_p = t >> 6;
    int o8 = (l >> 4) * 8;
    int irow = kg_p * 16 + (l & 15);
    short8 vf = *(const short8*)(TL + irow * 328 + o8);
    short8 vg = *(const short8*)(TL + irow * 328 + 32 + o8);
    size_t kgG = (size_t)b * 256 + (i0 >> 4) + kg_p;
    *(short8*)(fA + kgG * 512 + l * 8) = vf;
    *(short8*)(gB + kgG * 512 + l * 8) = vg;
  }
  // pack hA (o 64..319): 32 frags x 64 lanes over 512 threads
  #pragma unroll
  for (int q = 0; q < 4; ++q) {
    int slot = t + q * 512;
    int fr = slot >> 6, ll = slot & 63;
    int cg = fr >> 1, kcl = fr & 1;
    int orow = 64 + cg * 16 + (ll & 15);
    int pbase = kcl * 32 + (ll >> 4) * 8;
    short8 v;
    #pragma unroll
    for (int e = 0; e < 8; ++e) v[e] = (short)TL[(pbase + e) * 328 + orow];
    size_t idx = (((size_t)b * 16 + cg) * 128 + (i0 >> 5) + kcl) * 512 + ll * 8;
    *(short8*)(hA + idx) = v;
  }
}

// Kernel 2: online softmax stats (single pass). Block: 128 k-rows, 8 waves;
// gB streamed through LDS in 16-frag tiles (shared by all waves).
__global__ __launch_bounds__(512) void k_stats(
    const unsigned short* __restrict__ fA, const unsigned short* __restrict__ gB,
    float* __restrict__ m2, float* __restrict__ invD)
{
  __shared__ __align__(16) unsigned short sg[16 * 512];   // 16 KB
  const int bid = blockIdx.x;
  const int b = bid & 7, ktile = bid >> 3;
  const int t = threadIdx.x, w = t >> 6, l = t & 63;
  short8 afrag = *(const short8*)(fA +
      ((size_t)b * 256 + ktile * 8 + w) * 512 + l * 8);
  const float4* gsrc = (const float4*)(gB + (size_t)b * 256 * 512);
  f32x4 zero = {0.f, 0.f, 0.f, 0.f};
  float m[4] = {-1e30f, -1e30f, -1e30f, -1e30f};
  float s[4] = {0.f, 0.f, 0.f, 0.f};
  for (int jt = 0; jt < 16; ++jt) {
    __syncthreads();
    ((float4*)sg)[t]       = gsrc[(size_t)jt * 1024 + t];
    ((float4*)sg)[t + 512] = gsrc[(size_t)jt * 1024 + t + 512];
    __syncthreads();
    f32x4 d[16];
    #pragma unroll
    for (int jg = 0; jg < 16; ++jg) {
      short8 bfrag = *(const short8*)(sg + (jg * 64 + l) * 8);
      d[jg] = __builtin_amdgcn_mfma_f32_16x16x32_bf16(afrag, bfrag, zero, 0, 0, 0);
    }
    float cm[4] = {-1e30f, -1e30f, -1e30f, -1e30f};
    #pragma unroll
    for (int jg = 0; jg < 16; ++jg)
      #pragma unroll
      for (int r = 0; r < 4; ++r) cm[r] = fmaxf(cm[r], d[jg][r]);
    #pragma unroll
    for (int r = 0; r < 4; ++r) {
      float mn = fmaxf(m[r], cm[r]);
      float a0 = 0.f;
      #pragma unroll
      for (int jg = 0; jg < 16; ++jg) a0 += exp2f(d[jg][r] - mn);
      s[r] = s[r] * exp2f(m[r] - mn) + a0;
      m[r] = mn;
    }
  }
  // merge across the 16 j-lanes (cols of the D frag)
  #pragma unroll
  for (int mk = 1; mk < 16; mk <<= 1)
    #pragma unroll
    for (int r = 0; r < 4; ++r) {
      float om = __shfl_xor(m[r], mk);
      float os = __shfl_xor(s[r], mk);
      float mn = fmaxf(m[r], om);
      s[r] = s[r] * exp2f(m[r] - mn) + os * exp2f(om - mn);
      m[r] = mn;
    }
  if ((l & 15) == 0) {
    #pragma unroll
    for (int r = 0; r < 4; ++r) {
      size_t idx = (size_t)b * NN + (ktile * 8 + w) * 16 + (l >> 4) * 4 + r;
      m2[idx] = m[r];
      invD[idx] = 1.0f / s[r];
    }
  }
}

// Kernel 3: out = gamma * (h @ softmax) + x.  Block: 256c x 128i, k-chunks
// of 64, double-buffered P-LDS, one barrier per chunk, 36 MFMA/wave/chunk.
__global__ __launch_bounds__(512) void k_out(
    const unsigned short* __restrict__ fA, const unsigned short* __restrict__ gB,
    const unsigned short* __restrict__ hA,
    const float* __restrict__ m2v, const float* __restrict__ invDv,
    const float* __restrict__ x, const float* __restrict__ gamma,
    float* __restrict__ out)
{
  __shared__ __align__(16) unsigned short pF[2 * 16 * 512];  // 2 x 16 KB
  const int bid = blockIdx.x;
  const int b = bid & 7, i0 = (bid >> 3) * 128;   // batch pinned to XCD
  const int t = threadIdx.x, w = t >> 6, l = t & 63;
  const int lr4 = (l >> 4) * 4, li = l & 15;
  short8 gfrag = *(const short8*)(gB +
      ((size_t)b * 256 + (i0 >> 4) + w) * 512 + l * 8);   // ig = w, whole kernel
  const float* m2 = m2v + (size_t)b * NN;
  const float* invD = invDv + (size_t)b * NN;
  f32x4 zero = {0.f, 0.f, 0.f, 0.f};
  f32x4 acc[2][8] = {};
  for (int ch = 0; ch < 64; ++ch) {
    unsigned short* pcur = pF + (ch & 1) * 8192;
    // --- S phase: 4 S-frags (k rows ch*64..+64, i cols i0+w*16..+16) ---
    #pragma unroll
    for (int kg2 = 0; kg2 < 4; ++kg2) {
      short8 afrag = *(const short8*)(fA +
          ((size_t)b * 256 + ch * 4 + kg2) * 512 + l * 8);
      f32x4 sfr = __builtin_amdgcn_mfma_f32_16x16x32_bf16(afrag, gfrag, zero, 0, 0, 0);
      int kb = ch * 64 + kg2 * 16 + lr4;
      float4 mm = *(const float4*)(m2 + kb);
      float4 dd = *(const float4*)(invD + kb);
      ushort4 pv;
      pv.x = f2b(exp2f(sfr[0] - mm.x) * dd.x);
      pv.y = f2b(exp2f(sfr[1] - mm.y) * dd.y);
      pv.z = f2b(exp2f(sfr[2] - mm.z) * dd.z);
      pv.w = f2b(exp2f(sfr[3] - mm.w) * dd.w);
      int kk = (kg2 & 1) * 16 + lr4;
      int kp2 = kg2 >> 1;
      *(ushort4*)(pcur + ((kp2 * 8 + w) * 64 + (((kk >> 3) << 4) | li)) * 8
                       + (kk & 7)) = pv;
    }
    __syncthreads();
    // --- PV phase: 32 MFMA/wave from LDS P-frags + global h A-frags ---
    short8 pf0[8], pf1[8];
    #pragma unroll
    for (int ig = 0; ig < 8; ++ig) {
      pf0[ig] = *(const short8*)(pcur + (ig * 64 + l) * 8);
      pf1[ig] = *(const short8*)(pcur + ((8 + ig) * 64 + l) * 8);
    }
    #pragma unroll
    for (int cg2 = 0; cg2 < 2; ++cg2) {
      const unsigned short* hbase = hA +
          (((size_t)b * 16 + w * 2 + cg2) * 128 + ch * 2) * 512 + l * 8;
      short8 hf0 = *(const short8*)(hbase);
      short8 hf1 = *(const short8*)(hbase + 512);
      #pragma unroll
      for (int ig = 0; ig < 8; ++ig) {
        acc[cg2][ig] = __builtin_amdgcn_mfma_f32_16x16x32_bf16(hf0, pf0[ig], acc[cg2][ig], 0, 0, 0);
        acc[cg2][ig] = __builtin_amdgcn_mfma_f32_16x16x32_bf16(hf1, pf1[ig], acc[cg2][ig], 0, 0, 0);
      }
    }
  }
  const float gm = gamma[0];
  #pragma unroll
  for (int cg2 = 0; cg2 < 2; ++cg2)
    #pragma unroll
    for (int ig = 0; ig < 8; ++ig)
      #pragma unroll
      for (int r = 0; r < 4; ++r) {
        int c = w * 32 + cg2 * 16 + lr4 + r;
        int i = i0 + ig * 16 + li;
        size_t off = ((size_t)b * CC + c) * NN + i;
        out[off] = gm * acc[cg2][ig][r] + x[off];
      }
}

extern "C" void kernel_launch(void* const* d_in, const int* in_sizes, int n_in,
                              void* d_out, int out_size, void* d_ws, size_t ws_size,
                              hipStream_t stream)
{
  const float* x     = (const float*)d_in[0];
  const float* Wf    = (const float*)d_in[1];
  const float* bf    = (const float*)d_in[2];
  const float* Wg    = (const float*)d_in[3];
  const float* bg    = (const float*)d_in[4];
  const float* Wh    = (const float*)d_in[5];
  const float* bh    = (const float*)d_in[6];
  const float* gamma = (const float*)d_in[7];
  float* out = (float*)d_out;

  char* wsb = (char*)d_ws;
  float* m2   = (float*)(wsb + 0);
  float* invD = (float*)(wsb + 131072);
  unsigned short* wA = (unsigned short*)(wsb + 262144);
  float* ball        = (float*)(wsb + 425984);
  unsigned short* fA = (unsigned short*)(wsb + 427520);
  unsigned short* gB = (unsigned short*)(wsb + 2524672);
  unsigned short* hA = (unsigned short*)(wsb + 4621824);

  k_wprep<<<40,  256, 0, stream>>>(Wf, bf, Wg, bg, Wh, bh, wA, ball);
  k_fgh  <<<512, 512, 0, stream>>>(x, wA, ball, fA, gB, hA);
  k_stats<<<256, 512, 0, stream>>>(fA, gB, m2, invD);
  k_out  <<<256, 512, 0, stream>>>(fA, gB, hA, m2, invD, x, gamma, out);
}